// Round 1
// baseline (366.417 us; speedup 1.0000x reference)
//
#include <hip/hip_runtime.h>

// ---------------------------------------------------------------------------
// Model_39676907883593: out = dropout(softmax((x1 @ (m @ n^T)) / 64)) @ q
//   B=16, S=2048, D=64, DV=512.  Dropout = JAX threefry, key 42, p_keep=0.75.
// Strategy:
//   prep: kT[s][d] = (m@n^T)^T / 64 -> split bf16 hi/lo ; x1 -> bf16 hi/lo ;
//         qT[dv][s] bf16.
//   main: flash-style scan over keys, NO max-subtraction softmax (scores are
//         small; exp cannot overflow fp32).  QK^T with 3-term split-bf16 MFMA
//         (fp32-accurate), PV as O^T = V^T * P^T in plain bf16 MFMA.
//   dropout: keep <=> threefry_bits(flat_idx) < 0xC0000000  (exact integer
//         form of uniform()<0.75).  Partitionable-threefry semantics
//         (bits = o0 ^ o1 of threefry2x32(key=(0,42), hi=0, lo=idx)).
// ---------------------------------------------------------------------------

#define THREEFRY_PARTITIONABLE 1   // flip to 0 for legacy split-iota JAX PRNG

typedef short  s8v __attribute__((ext_vector_type(8)));
typedef float  f4v __attribute__((ext_vector_type(4)));

__device__ __forceinline__ unsigned short f2bf(float f) {
  unsigned int u = __float_as_uint(f);
  u += 0x7fffu + ((u >> 16) & 1u);           // RNE
  return (unsigned short)(u >> 16);
}
__device__ __forceinline__ float bf2f(unsigned short h) {
  return __uint_as_float(((unsigned int)h) << 16);
}

// ---- threefry2x32, key = (0, 42)  (jax.random.key(42)) --------------------
__device__ __forceinline__ void tf2x32(unsigned int& x0, unsigned int& x1) {
  const unsigned int K0 = 0u, K1 = 42u, K2 = 0x1BD11BDAu ^ K0 ^ K1;
  x0 += K0; x1 += K1;
#define TF_R(r) { x0 += x1; x1 = (x1 << r) | (x1 >> (32 - r)); x1 ^= x0; }
  TF_R(13) TF_R(15) TF_R(26) TF_R(6)
  x0 += K1; x1 += K2 + 1u;
  TF_R(17) TF_R(29) TF_R(16) TF_R(24)
  x0 += K2; x1 += K0 + 2u;
  TF_R(13) TF_R(15) TF_R(26) TF_R(6)
  x0 += K0; x1 += K1 + 3u;
  TF_R(17) TF_R(29) TF_R(16) TF_R(24)
  x0 += K1; x1 += K2 + 4u;
  TF_R(13) TF_R(15) TF_R(26) TF_R(6)
  x0 += K2; x1 += K0 + 5u;
#undef TF_R
}

__device__ __forceinline__ unsigned int jax_bits(unsigned int idx) {
#if THREEFRY_PARTITIONABLE
  unsigned int x0 = 0u, x1 = idx;            // counter = (hi=0, lo=idx)
  tf2x32(x0, x1);
  return x0 ^ x1;                            // 32-bit xor-fold
#else
  const unsigned int HALF = 33554432u;       // 16*2048*2048 / 2
  bool first = idx < HALF;
  unsigned int lo = first ? idx : (idx - HALF);
  unsigned int x0 = lo, x1 = lo + HALF;
  tf2x32(x0, x1);
  return first ? x0 : x1;
#endif
}

__device__ __forceinline__ f4v mfma16(s8v a, s8v b, f4v c) {
  return __builtin_amdgcn_mfma_f32_16x16x32_bf16(a, b, c, 0, 0, 0);
}

// ---------------------------------------------------------------------------
// prep kernels
// ---------------------------------------------------------------------------
__global__ void transpose_m(const float* __restrict__ m, float* __restrict__ mT) {
  int i = blockIdx.x * 256 + threadIdx.x;    // 0..32767
  int dv = i >> 6, d = i & 63;
  mT[i] = m[d * 512 + dv];                   // mT[dv][d]
}

__global__ void split_x(const float* __restrict__ x, unsigned short* __restrict__ hi,
                        unsigned short* __restrict__ lo, int nElem) {
  int i = blockIdx.x * 256 + threadIdx.x;
  if (i < nElem) {
    float v = x[i];
    unsigned short h = f2bf(v);
    hi[i] = h;
    lo[i] = f2bf(v - bf2f(h));
  }
}

// K[s][d] = (sum_dv m[d][dv]*n[s][dv]) / 64, split to bf16 hi/lo
__global__ void build_k(const float* __restrict__ mT, const float* __restrict__ n,
                        unsigned short* __restrict__ Khi, unsigned short* __restrict__ Klo) {
  int s = blockIdx.x;                        // 2048
  int d = threadIdx.x;                       // 64
  const float* nrow = n + (size_t)s * 512;
  float a0 = 0.f, a1 = 0.f, a2 = 0.f, a3 = 0.f;
  for (int dv = 0; dv < 512; dv += 4) {
    a0 = fmaf(mT[(dv + 0) * 64 + d], nrow[dv + 0], a0);
    a1 = fmaf(mT[(dv + 1) * 64 + d], nrow[dv + 1], a1);
    a2 = fmaf(mT[(dv + 2) * 64 + d], nrow[dv + 2], a2);
    a3 = fmaf(mT[(dv + 3) * 64 + d], nrow[dv + 3], a3);
  }
  float k = ((a0 + a1) + (a2 + a3)) * 0.015625f;   // fold 1/64 scale
  unsigned short h = f2bf(k);
  Khi[s * 64 + d] = h;
  Klo[s * 64 + d] = f2bf(k - bf2f(h));
}

// qT[dv][s] = bf16(q[s][dv])
__global__ void transpose_q(const float* __restrict__ q, unsigned short* __restrict__ qT) {
  __shared__ unsigned short tile[64][65];
  int s0 = (blockIdx.x >> 3) * 64;
  int d0 = (blockIdx.x & 7) * 64;
  int t = threadIdx.x;                       // 256
#pragma unroll
  for (int k = 0; k < 16; ++k) {
    int lin = t + k * 256;                   // 0..4095
    int r = lin >> 6, c = lin & 63;          // r: s-row, c: dv-col
    tile[c][r] = f2bf(q[(size_t)(s0 + r) * 512 + d0 + c]);
  }
  __syncthreads();
#pragma unroll
  for (int k = 0; k < 16; ++k) {
    int lin = t + k * 256;
    int rr = lin >> 6, cc = lin & 63;        // rr: dv, cc: s
    qT[(size_t)(d0 + rr) * 2048 + s0 + cc] = tile[rr][cc];
  }
}

// ---------------------------------------------------------------------------
// main fused kernel: 256 blocks (b,rowTile) x 512 threads (8 waves)
//   per block: 128 rows, full key scan in 16 iters of BN=128
// ---------------------------------------------------------------------------
__global__ __launch_bounds__(512, 2) void attn_main(
    const unsigned short* __restrict__ Xhi, const unsigned short* __restrict__ Xlo,
    const unsigned short* __restrict__ Khi, const unsigned short* __restrict__ Klo,
    const unsigned short* __restrict__ qT, float* __restrict__ out) {
  // LDS (pad inner dims to 72/136 elems -> row stride +4 banks, ~conflict-free)
  __shared__ unsigned short Xs[2][128][72];  // x1 hi/lo tile            36,864 B
  __shared__ unsigned short Ks[2][128][72];  // kT hi/lo key-tile        36,864 B
  __shared__ unsigned short Ps[128][136];    // probs (bf16)             34,816 B
  __shared__ float rsum[128];                //                             512 B

  const int tid  = threadIdx.x;
  const int wave = tid >> 6;
  const int lane = tid & 63;
  const int l15  = lane & 15;
  const int quad = lane >> 4;

  const int b    = blockIdx.x >> 4;
  const int row0 = (blockIdx.x & 15) * 128;

  // ---- stage X tile (128 rows x 64 d, hi+lo) ----
#pragma unroll
  for (int p = 0; p < 2; ++p) {
    int seg = tid + p * 512;                 // 0..1023
    int r = seg >> 3, c = (seg & 7) * 8;
    const size_t g = ((size_t)(b * 2048 + row0 + r)) * 64 + c;
    *(uint4*)&Xs[0][r][c] = *(const uint4*)&Xhi[g];
    *(uint4*)&Xs[1][r][c] = *(const uint4*)&Xlo[g];
  }

  f4v acc[4][8];                             // O^T: [mt(dv)][nt(row)]
#pragma unroll
  for (int mt = 0; mt < 4; ++mt)
#pragma unroll
    for (int nt = 0; nt < 8; ++nt) acc[mt][nt] = f4v{0.f, 0.f, 0.f, 0.f};
  float rs[4] = {0.f, 0.f, 0.f, 0.f};        // rowsum partials (rows wave*16+quad*4+r)

  for (int it = 0; it < 16; ++it) {
    const int kt = it * 128;
    __syncthreads();                         // prev P reads done; Ks free
    // ---- stage K tile (128 keys x 64 d, hi+lo) ----
#pragma unroll
    for (int p = 0; p < 2; ++p) {
      int seg = tid + p * 512;
      int kk = seg >> 3, c = (seg & 7) * 8;
      const size_t g = ((size_t)(kt + kk)) * 64 + c;
      *(uint4*)&Ks[0][kk][c] = *(const uint4*)&Khi[g];
      *(uint4*)&Ks[1][kk][c] = *(const uint4*)&Klo[g];
    }
    __syncthreads();

    // ---- QK^T: wave handles its 16 rows x all 128 keys ----
    // A-frag: X[row = wave*16 + l15][k = kstep*32 + quad*8 + j]
    s8v Ah0 = *(const s8v*)&Xs[0][wave * 16 + l15][quad * 8];
    s8v Ah1 = *(const s8v*)&Xs[0][wave * 16 + l15][32 + quad * 8];
    s8v Al0 = *(const s8v*)&Xs[1][wave * 16 + l15][quad * 8];
    s8v Al1 = *(const s8v*)&Xs[1][wave * 16 + l15][32 + quad * 8];

    for (int nt = 0; nt < 8; ++nt) {
      const int key = nt * 16 + l15;
      s8v Bh0 = *(const s8v*)&Ks[0][key][quad * 8];
      s8v Bh1 = *(const s8v*)&Ks[0][key][32 + quad * 8];
      s8v Bl0 = *(const s8v*)&Ks[1][key][quad * 8];
      s8v Bl1 = *(const s8v*)&Ks[1][key][32 + quad * 8];
      f4v c = {0.f, 0.f, 0.f, 0.f};
      c = mfma16(Ah0, Bh0, c);  c = mfma16(Ah1, Bh1, c);   // hi*hi
      c = mfma16(Ah0, Bl0, c);  c = mfma16(Ah1, Bl1, c);   // hi*lo
      c = mfma16(Al0, Bh0, c);  c = mfma16(Al1, Bh1, c);   // lo*hi
      // C layout: row = quad*4 + r (in wave's 16-row tile), col = l15
#pragma unroll
      for (int r = 0; r < 4; ++r) {
        float e = __expf(c[r]);
        rs[r] += e;                          // softmax denom: UNmasked
        const int row_local = wave * 16 + quad * 4 + r;
        const unsigned int gkey = (unsigned int)(kt + nt * 16 + l15);
        const unsigned int idx =
            ((unsigned int)(b * 2048 + row0 + row_local)) * 2048u + gkey;
        const unsigned int bits = jax_bits(idx);
        const float pe = (bits < 0xC0000000u) ? e : 0.0f;
        Ps[row_local][nt * 16 + l15] = f2bf(pe);
      }
    }
    __syncthreads();                         // P complete

    // ---- PV as O^T = V^T * P^T  (wave owns dv slice [wave*64, +64)) ----
#pragma unroll
    for (int ks = 0; ks < 4; ++ks) {
      s8v Va[4];
#pragma unroll
      for (int mt = 0; mt < 4; ++mt) {
        const size_t g =
            (size_t)(wave * 64 + mt * 16 + l15) * 2048 + kt + ks * 32 + quad * 8;
        Va[mt] = *(const s8v*)&qT[g];        // A: V^T[dv][k]
      }
#pragma unroll
      for (int nt = 0; nt < 8; ++nt) {
        s8v Pb = *(const s8v*)&Ps[nt * 16 + l15][ks * 32 + quad * 8];  // B: P^T[k][row]
#pragma unroll
        for (int mt = 0; mt < 4; ++mt) acc[mt][nt] = mfma16(Va[mt], Pb, acc[mt][nt]);
      }
    }
  }

  // ---- rowsum reduction: sum over l15 (keys were strided by l15 mod 16) ----
#pragma unroll
  for (int r = 0; r < 4; ++r) {
    float v = rs[r];
    v += __shfl_xor(v, 1);  v += __shfl_xor(v, 2);
    v += __shfl_xor(v, 4);  v += __shfl_xor(v, 8);
    if (l15 == 0) rsum[wave * 16 + quad * 4 + r] = v;
  }
  __syncthreads();

  // ---- normalize + store: out[b][row][dv] = acc / (0.75 * rowsum) ----
#pragma unroll
  for (int nt = 0; nt < 8; ++nt) {
    const int row = row0 + nt * 16 + l15;
    const float inv = 1.0f / (0.75f * rsum[nt * 16 + l15]);
    const size_t base = ((size_t)(b * 2048 + row)) * 512;
#pragma unroll
    for (int mt = 0; mt < 4; ++mt) {
#pragma unroll
      for (int r = 0; r < 4; ++r) {
        const int dv = wave * 64 + mt * 16 + quad * 4 + r;
        out[base + dv] = acc[mt][nt][r] * inv;
      }
    }
  }
}

// ---------------------------------------------------------------------------
extern "C" void kernel_launch(void* const* d_in, const int* in_sizes, int n_in,
                              void* d_out, int out_size, void* d_ws, size_t ws_size,
                              hipStream_t stream) {
  (void)in_sizes; (void)n_in; (void)out_size; (void)ws_size;
  const float* x1 = (const float*)d_in[0];   // [16][2048][64]
  const float* m  = (const float*)d_in[1];   // [64][512]
  const float* n  = (const float*)d_in[2];   // [2048][512]
  const float* q  = (const float*)d_in[3];   // [2048][512]
  float* out = (float*)d_out;                // [16][2048][512]

  // workspace layout (total ~10.6 MB)
  char* ws = (char*)d_ws;
  float*          mT  = (float*)(ws + 0);                    // 512*64*4      = 131072
  unsigned short* Khi = (unsigned short*)(ws + 131072);      // 2048*64*2     = 262144
  unsigned short* Klo = (unsigned short*)(ws + 393216);      // 262144
  unsigned short* Xhi = (unsigned short*)(ws + 655360);      // 16*2048*64*2  = 4194304
  unsigned short* Xlo = (unsigned short*)(ws + 4849664);     // 4194304
  unsigned short* qT  = (unsigned short*)(ws + 9043968);     // 512*2048*2    = 2097152

  transpose_m<<<128, 256, 0, stream>>>(m, mT);
  split_x<<<8192, 256, 0, stream>>>(x1, Xhi, Xlo, 16 * 2048 * 64);
  build_k<<<2048, 64, 0, stream>>>(mT, n, Khi, Klo);
  transpose_q<<<256, 256, 0, stream>>>(q, qT);
  attn_main<<<256, 512, 0, stream>>>(Xhi, Xlo, Khi, Klo, qT, out);
}

// Round 3
// 321.381 us; speedup vs baseline: 1.1401x; 1.1401x over previous
//
#include <hip/hip_runtime.h>

// ---------------------------------------------------------------------------
// Model_39676907883593: out = dropout(softmax((x1 @ (m @ n^T)) / 64)) @ q
//   B=16, S=2048, D=64, DV=512.  Dropout = JAX threefry, key 42, p_keep=0.75.
// R3: R2 structure with prep grid bug fixed (x1 cast region was 8x oversized
//     and unguarded -> OOB read/write -> abort).  x1 elems = 2,097,152:
//     1024 blocks x 256 thr x 8 elems.
// ---------------------------------------------------------------------------

typedef short  s8v __attribute__((ext_vector_type(8)));
typedef float  f4v __attribute__((ext_vector_type(4)));

__device__ __forceinline__ unsigned short f2bf(float f) {
  unsigned int u = __float_as_uint(f);
  u += 0x7fffu + ((u >> 16) & 1u);           // RNE
  return (unsigned short)(u >> 16);
}
__device__ __forceinline__ float bf2f(unsigned short h) {
  return __uint_as_float(((unsigned int)h) << 16);
}
__device__ __forceinline__ unsigned int pack_bf2(float a, float b) {
  unsigned int ua = __float_as_uint(a);
  ua += 0x7fffu + ((ua >> 16) & 1u);
  unsigned int ub = __float_as_uint(b);
  ub += 0x7fffu + ((ub >> 16) & 1u);
  return (ua >> 16) | (ub & 0xffff0000u);
}

// rotl via v_alignbit: ({x,x} >> (32-r)) == rotl(x, r)
__device__ __forceinline__ unsigned int rotl(unsigned int x, unsigned int r) {
  return __builtin_amdgcn_alignbit(x, x, 32u - r);
}

// ---- threefry2x32, key = (0, 42); partitionable counter (0, idx) ----------
__device__ __forceinline__ unsigned int jax_bits(unsigned int idx) {
  const unsigned int K0 = 0u, K1 = 42u, K2 = 0x1BD11BDAu ^ K0 ^ K1;
  unsigned int x0 = 0u, x1 = idx;
  x0 += K0; x1 += K1;
#define TF_R(r) { x0 += x1; x1 = rotl(x1, r); x1 ^= x0; }
  TF_R(13) TF_R(15) TF_R(26) TF_R(6)
  x0 += K1; x1 += K2 + 1u;
  TF_R(17) TF_R(29) TF_R(16) TF_R(24)
  x0 += K2; x1 += K0 + 2u;
  TF_R(13) TF_R(15) TF_R(26) TF_R(6)
  x0 += K0; x1 += K1 + 3u;
  TF_R(17) TF_R(29) TF_R(16) TF_R(24)
  x0 += K1; x1 += K2 + 4u;
  TF_R(13) TF_R(15) TF_R(26) TF_R(6)
  x0 += K2; x1 += K0 + 5u;
#undef TF_R
  return x0 ^ x1;
}

__device__ __forceinline__ f4v mfma16(s8v a, s8v b, f4v c) {
  return __builtin_amdgcn_mfma_f32_16x16x32_bf16(a, b, c, 0, 0, 0);
}

// ---------------------------------------------------------------------------
// prep_misc: blockIdx [0,1024)    -> x1 cast to bf16 (8 elems/thread, 2.1M)
//            [1024,1280)          -> transpose_q (qT[dv][s] bf16)
//            [1280,1408)          -> transpose_m (mT[dv][d] fp32)
// ---------------------------------------------------------------------------
__global__ void prep_misc(const float* __restrict__ x1, const float* __restrict__ q,
                          const float* __restrict__ m,
                          unsigned short* __restrict__ Xhi,
                          unsigned short* __restrict__ qT,
                          float* __restrict__ mT) {
  const int blk = blockIdx.x;
  const int t = threadIdx.x;
  if (blk < 1024) {                          // ---- cast x1 -> bf16 ----
    const int i = (blk * 256 + t) * 8;       // 2,097,152 elems total
    float4 a = *(const float4*)&x1[i];
    float4 b = *(const float4*)&x1[i + 4];
    ushort4 o0, o1;
    o0.x = f2bf(a.x); o0.y = f2bf(a.y); o0.z = f2bf(a.z); o0.w = f2bf(a.w);
    o1.x = f2bf(b.x); o1.y = f2bf(b.y); o1.z = f2bf(b.z); o1.w = f2bf(b.w);
    *(ushort4*)&Xhi[i] = o0;
    *(ushort4*)&Xhi[i + 4] = o1;
  } else if (blk < 1280) {                   // ---- transpose_q ----
    __shared__ unsigned short tile[64][65];
    const int bb = blk - 1024;               // 0..255
    const int s0 = (bb >> 3) * 64;
    const int d0 = (bb & 7) * 64;
#pragma unroll
    for (int k = 0; k < 16; ++k) {
      int lin = t + k * 256;
      int r = lin >> 6, c = lin & 63;
      tile[c][r] = f2bf(q[(size_t)(s0 + r) * 512 + d0 + c]);
    }
    __syncthreads();
#pragma unroll
    for (int k = 0; k < 16; ++k) {
      int lin = t + k * 256;
      int rr = lin >> 6, cc = lin & 63;
      qT[(size_t)(d0 + rr) * 2048 + s0 + cc] = tile[rr][cc];
    }
  } else {                                   // ---- transpose_m ----
    const int i = (blk - 1280) * 256 + t;    // 0..32767
    int dv = i >> 6, d = i & 63;
    mT[i] = m[d * 512 + dv];
  }
}

// K[s][d] = (sum_dv m[d][dv]*n[s][dv]) / 64, split to bf16 hi/lo
__global__ void build_k(const float* __restrict__ mT, const float* __restrict__ n,
                        unsigned short* __restrict__ Khi, unsigned short* __restrict__ Klo) {
  const int s = blockIdx.x * 4 + (threadIdx.x >> 6);  // 512 blocks x 4 rows
  const int d = threadIdx.x & 63;
  const float* nrow = n + (size_t)s * 512;
  float a0 = 0.f, a1 = 0.f, a2 = 0.f, a3 = 0.f;
  for (int dv = 0; dv < 512; dv += 4) {
    a0 = fmaf(mT[(dv + 0) * 64 + d], nrow[dv + 0], a0);
    a1 = fmaf(mT[(dv + 1) * 64 + d], nrow[dv + 1], a1);
    a2 = fmaf(mT[(dv + 2) * 64 + d], nrow[dv + 2], a2);
    a3 = fmaf(mT[(dv + 3) * 64 + d], nrow[dv + 3], a3);
  }
  float k = ((a0 + a1) + (a2 + a3)) * 0.015625f;     // fold 1/64
  unsigned short h = f2bf(k);
  Khi[s * 64 + d] = h;
  Klo[s * 64 + d] = f2bf(k - bf2f(h));
}

// ---------------------------------------------------------------------------
// main fused kernel: 512 blocks (b, rowTile64) x 512 threads (8 waves)
//   QK^T computes S^T (A = K keys, B = X rows): lane holds 4 consecutive keys
//   of one row -> packed b64 P writes, consecutive threefry counters.
//   wave w: QK rows (w&3)*16..+16, keys (w>>2)*64..+64 of the 128-key iter.
//   PV: wave w owns dv slice [w*64, w*64+64), O^T = V^T * P^T.
// ---------------------------------------------------------------------------
__global__ __launch_bounds__(512, 4) void attn_main(
    const unsigned short* __restrict__ Xhi,
    const unsigned short* __restrict__ Khi, const unsigned short* __restrict__ Klo,
    const unsigned short* __restrict__ qT, float* __restrict__ out) {
  __shared__ unsigned short Ks[2][128][72];  // K hi/lo key-tile   36,864 B
  __shared__ unsigned short Ps[64][136];     // probs bf16         17,408 B
  __shared__ float rsum[2][64];              //                       512 B

  const int tid  = threadIdx.x;
  const int wave = tid >> 6;
  const int lane = tid & 63;
  const int l15  = lane & 15;
  const int quad = lane >> 4;

  const int b    = blockIdx.x >> 5;          // 16 batches
  const int row0 = (blockIdx.x & 31) * 64;   // 32 row tiles

  const int qk_row = (wave & 3) * 16 + l15;  // row (local) this lane scores
  const int qk_kg  = (wave >> 2) * 64;       // key-group base within iter

  // ---- X B-frags (hi only), iter-invariant, in registers ----
  const size_t xg = ((size_t)(b * 2048 + row0 + qk_row)) * 64 + quad * 8;
  const s8v X0 = *(const s8v*)&Xhi[xg];
  const s8v X1 = *(const s8v*)&Xhi[xg + 32];

  f4v acc[4][4];                             // O^T: [mt(dv 16)][nt(row 16)]
#pragma unroll
  for (int mt = 0; mt < 4; ++mt)
#pragma unroll
    for (int nt = 0; nt < 4; ++nt) acc[mt][nt] = f4v{0.f, 0.f, 0.f, 0.f};
  float rs = 0.f;                            // rowsum partial for row qk_row

  const unsigned int idx_row =
      ((unsigned int)(b * 2048 + row0 + qk_row)) * 2048u;

  for (int it = 0; it < 16; ++it) {
    const int kt = it * 128;
    __syncthreads();                         // prev iter's Ps reads done
    // ---- stage K tile (128 keys x 64 d, hi+lo): 4 b128 per thread ----
    {
      const int kk = tid >> 2, c = (tid & 3) * 16;
      const size_t g = ((size_t)(kt + kk)) * 64 + c;
      *(uint4*)&Ks[0][kk][c]     = *(const uint4*)&Khi[g];
      *(uint4*)&Ks[0][kk][c + 8] = *(const uint4*)&Khi[g + 8];
      *(uint4*)&Ks[1][kk][c]     = *(const uint4*)&Klo[g];
      *(uint4*)&Ks[1][kk][c + 8] = *(const uint4*)&Klo[g + 8];
    }
    __syncthreads();

    // ---- QK^T -> S^T: 4 key-tiles of 16 for this wave's key group ----
#pragma unroll
    for (int nt = 0; nt < 4; ++nt) {
      const int key = qk_kg + nt * 16 + l15;             // A: K[key][d]
      s8v Kh0 = *(const s8v*)&Ks[0][key][quad * 8];
      s8v Kh1 = *(const s8v*)&Ks[0][key][32 + quad * 8];
      s8v Kl0 = *(const s8v*)&Ks[1][key][quad * 8];
      s8v Kl1 = *(const s8v*)&Ks[1][key][32 + quad * 8];
      f4v c = {0.f, 0.f, 0.f, 0.f};
      c = mfma16(Kh0, X0, c);  c = mfma16(Kh1, X1, c);   // Khi . x
      c = mfma16(Kl0, X0, c);  c = mfma16(Kl1, X1, c);   // Klo . x
      // C: m = key quad*4+r (consecutive keys), n = row l15
      const unsigned int idx0 = idx_row + (unsigned int)(kt + qk_kg + nt * 16 + quad * 4);
      float p[4];
#pragma unroll
      for (int r = 0; r < 4; ++r) {
        float e = __expf(c[r]);
        rs += e;                                          // denom: unmasked
        const unsigned int bits = jax_bits(idx0 + r);
        p[r] = (bits < 0xC0000000u) ? e : 0.0f;
      }
      const unsigned int p01 = pack_bf2(p[0], p[1]);
      const unsigned int p23 = pack_bf2(p[2], p[3]);
      *(uint2*)&Ps[(wave & 3) * 16 + l15][qk_kg + nt * 16 + quad * 4] =
          make_uint2(p01, p23);
    }
    __syncthreads();                         // P complete

    // ---- PV: O^T = V^T * P^T, wave owns dv [wave*64, +64) ----
#pragma unroll
    for (int ks = 0; ks < 4; ++ks) {         // 32-key chunks
      s8v Va[4];
#pragma unroll
      for (int mt = 0; mt < 4; ++mt) {
        const size_t g =
            (size_t)(wave * 64 + mt * 16 + l15) * 2048 + kt + ks * 32 + quad * 8;
        Va[mt] = *(const s8v*)&qT[g];        // A: V^T[dv][k]
      }
#pragma unroll
      for (int nt = 0; nt < 4; ++nt) {
        s8v Pb = *(const s8v*)&Ps[nt * 16 + l15][ks * 32 + quad * 8];  // B: P[row][k]
#pragma unroll
        for (int mt = 0; mt < 4; ++mt) acc[mt][nt] = mfma16(Va[mt], Pb, acc[mt][nt]);
      }
    }
  }

  // ---- rowsum: sum across quads (lanes sharing l15), then across key-groups
  {
    float v = rs;
    v += __shfl_xor(v, 16);
    v += __shfl_xor(v, 32);
    if (quad == 0) rsum[wave >> 2][(wave & 3) * 16 + l15] = v;
  }
  __syncthreads();

  // ---- normalize + store: out[b][row][dv] = acc / (0.75 * rowsum) ----
#pragma unroll
  for (int nt = 0; nt < 4; ++nt) {
    const int rloc = nt * 16 + l15;
    const int row = row0 + rloc;
    const float inv = 1.0f / (0.75f * (rsum[0][rloc] + rsum[1][rloc]));
    const size_t base = ((size_t)(b * 2048 + row)) * 512 + wave * 64;
#pragma unroll
    for (int mt = 0; mt < 4; ++mt) {
      f4v v = acc[mt][nt];
      v[0] *= inv; v[1] *= inv; v[2] *= inv; v[3] *= inv;
      *(f4v*)&out[base + mt * 16 + quad * 4] = v;
    }
  }
}

// ---------------------------------------------------------------------------
extern "C" void kernel_launch(void* const* d_in, const int* in_sizes, int n_in,
                              void* d_out, int out_size, void* d_ws, size_t ws_size,
                              hipStream_t stream) {
  (void)in_sizes; (void)n_in; (void)out_size; (void)ws_size;
  const float* x1 = (const float*)d_in[0];   // [16][2048][64]
  const float* m  = (const float*)d_in[1];   // [64][512]
  const float* n  = (const float*)d_in[2];   // [2048][512]
  const float* q  = (const float*)d_in[3];   // [2048][512]
  float* out = (float*)d_out;                // [16][2048][512]

  char* ws = (char*)d_ws;
  float*          mT  = (float*)(ws + 0);                  // 131,072
  unsigned short* Khi = (unsigned short*)(ws + 131072);    // 262,144
  unsigned short* Klo = (unsigned short*)(ws + 393216);    // 262,144
  unsigned short* Xhi = (unsigned short*)(ws + 655360);    // 4,194,304 (used: 4,194,304/8... 2,097,152*2 B)
  unsigned short* qT  = (unsigned short*)(ws + 4849664);   // 2,097,152

  prep_misc<<<1408, 256, 0, stream>>>(x1, q, m, Xhi, qT, mT);
  build_k<<<512, 256, 0, stream>>>(mT, n, Khi, Klo);
  attn_main<<<512, 512, 0, stream>>>(Xhi, Khi, Klo, qT, out);
}